// Round 3
// baseline (88.196 us; speedup 1.0000x reference)
//
#include <hip/hip_runtime.h>

namespace {
constexpr int Wd = 160, Hd = 192, Dd = 160, Bd = 2;
constexpr int HW = Hd * Wd;
constexpr int THREADS = 320;              // 5 waves; 8 rows x 40 strips, ALL compute
constexpr int ROWS_OUT = 8;
constexpr int ROWS_LDS = 10;              // incl. h-halo
constexpr int STRIPS = 40;
constexpr int RS = 164;                   // LDS row stride (floats), data at [0..159]
constexpr int DCHUNK = 10;
constexpr int NCHUNK = Dd / DCHUNK;       // 16
constexpr int HGROUPS = Hd / ROWS_OUT;    // 24
constexpr int NTASK = 2 * ROWS_LDS * STRIPS;  // 800 staging tasks (2 tensors)
constexpr float EPS = 1e-8f;
}

__global__ __launch_bounds__(THREADS) void sobel_loss_kernel(
    const float* __restrict__ pred, const float* __restrict__ targ,
    float* __restrict__ out) {
  // [tensor][arr: 0=sw,1=dw][row][RS] — single buffer, 26.2 KB
  __shared__ float lds[2][2][ROWS_LDS][RS];
  const int tid = threadIdx.x;
  const int h0 = blockIdx.x * ROWS_OUT;
  const int d0 = blockIdx.y * DCHUNK;
  const size_t volOff = (size_t)blockIdx.z * Dd * HW;
  const float* pb = pred + volOff;
  const float* tb = targ + volOff;

  // ---- staging task decode (2.5 tasks/thread, loop-invariant) ----
  const float* gp[3];
  float* dsw[3];
  float* ddw[3];
  bool okv[3], rvv[3], sl0[3], sr39[3];
#pragma unroll
  for (int u = 0; u < 3; ++u) {
    const int idx = tid + THREADS * u;
    const bool ok = (idx < NTASK);
    const int ic = ok ? idx : 0;
    const int t_ = ic / (ROWS_LDS * STRIPS);
    const int rem = ic - t_ * (ROWS_LDS * STRIPS);
    const int r8 = rem / STRIPS;
    const int s = rem - r8 * STRIPS;
    const int hh = h0 - 1 + r8;
    const bool rv = ok && ((unsigned)hh < (unsigned)Hd);
    okv[u] = ok; rvv[u] = rv;
    sl0[u] = (s > 0); sr39[u] = (s < STRIPS - 1);
    gp[u] = (t_ ? tb : pb) + (size_t)(rv ? hh : 0) * Wd + s * 4;
    dsw[u] = &lds[t_][0][r8][s * 4];
    ddw[u] = &lds[t_][1][r8][s * 4];
  }

  float4 xm[3]; float xlv[3], xrv[3];
  float4 swv[3], dwv[3];

  auto GLOADX = [&](int d) {
    const bool dok = (unsigned)d < (unsigned)Dd;
    const size_t so = (size_t)d * HW;
#pragma unroll
    for (int u = 0; u < 3; ++u) {
      float4 v = make_float4(0.f, 0.f, 0.f, 0.f);
      float l = 0.f, rr = 0.f;
      if (dok && rvv[u]) {
        v = *reinterpret_cast<const float4*>(gp[u] + so);
        if (sl0[u]) l = gp[u][so - 1];
        if (sr39[u]) rr = gp[u][so + 4];
      }
      xm[u] = v; xlv[u] = l; xrv[u] = rr;
    }
  };
  auto ROWCONV = [&]() {
#pragma unroll
    for (int u = 0; u < 3; ++u) {
      const float x0 = xlv[u], x1 = xm[u].x, x2 = xm[u].y, x3 = xm[u].z,
                  x4 = xm[u].w, x5 = xrv[u];
      swv[u].x = x0 + 2.f * x1 + x2;  dwv[u].x = x2 - x0;
      swv[u].y = x1 + 2.f * x2 + x3;  dwv[u].y = x3 - x1;
      swv[u].z = x2 + 2.f * x3 + x4;  dwv[u].z = x4 - x2;
      swv[u].w = x3 + 2.f * x4 + x5;  dwv[u].w = x5 - x3;
    }
  };
  auto LDSW = [&]() {
#pragma unroll
    for (int u = 0; u < 3; ++u) {
      if (okv[u]) {
        *reinterpret_cast<float4*>(dsw[u]) = swv[u];
        *reinterpret_cast<float4*>(ddw[u]) = dwv[u];
      }
    }
  };

  // ---- compute decode: output row r (0..7), strip cs (0..39) ----
  const int r = tid / STRIPS;
  const int s4 = (tid - r * STRIPS) * 4;

  // rolling state [slot][tensor][j]
  float A[3][2][4], B[3][2][4], C[3][2][4];

  auto HCONV = [&](int slot) {
#pragma unroll
    for (int t_ = 0; t_ < 2; ++t_) {
      const float4 sm = *reinterpret_cast<const float4*>(&lds[t_][0][r][s4]);
      const float4 s0 = *reinterpret_cast<const float4*>(&lds[t_][0][r + 1][s4]);
      const float4 sp = *reinterpret_cast<const float4*>(&lds[t_][0][r + 2][s4]);
      const float4 dm = *reinterpret_cast<const float4*>(&lds[t_][1][r][s4]);
      const float4 dd = *reinterpret_cast<const float4*>(&lds[t_][1][r + 1][s4]);
      const float4 dp = *reinterpret_cast<const float4*>(&lds[t_][1][r + 2][s4]);
      const float smv[4] = {sm.x, sm.y, sm.z, sm.w};
      const float s0v[4] = {s0.x, s0.y, s0.z, s0.w};
      const float spv[4] = {sp.x, sp.y, sp.z, sp.w};
      const float dmv[4] = {dm.x, dm.y, dm.z, dm.w};
      const float ddv[4] = {dd.x, dd.y, dd.z, dd.w};
      const float dpv[4] = {dp.x, dp.y, dp.z, dp.w};
#pragma unroll
      for (int j = 0; j < 4; ++j) {
        A[slot][t_][j] = smv[j] + 2.f * s0v[j] + spv[j];
        B[slot][t_][j] = dmv[j] + 2.f * ddv[j] + dpv[j];
        C[slot][t_][j] = spv[j] - smv[j];
      }
    }
  };

  float acc = 0.f;

  // ---- prologue ----
  GLOADX(d0 - 1); ROWCONV(); LDSW();         // LDS <- slice d0-1
  GLOADX(d0);
  __syncthreads();
  ROWCONV();                                  // regs <- slice d0
  HCONV(0);                                   // state0 <- slice d0-1
  __syncthreads();
  LDSW();                                     // LDS <- slice d0
  GLOADX(d0 + 1);
  __syncthreads();
  ROWCONV();                                  // regs <- slice d0+1
  HCONV(1);                                   // state1 <- slice d0
  __syncthreads();

  // ---- main loop, fully unrolled: output slice d0+k ----
#pragma unroll
  for (int k = 0; k < DCHUNK; ++k) {
    LDSW();                                   // LDS <- slice d0+1+k
    if (k < DCHUNK - 1) GLOADX(d0 + 2 + k);
    __syncthreads();
    if (k < DCHUNK - 1) ROWCONV();            // regs <- slice d0+2+k
    const int i0 = k % 3, i1 = (k + 1) % 3, i2 = (k + 2) % 3;
    HCONV(i2);                                // state <- slice d0+1+k
#pragma unroll
    for (int j = 0; j < 4; ++j) {
      float gx = B[i0][0][j] + 2.f * B[i1][0][j] + B[i2][0][j];
      float gy = C[i0][0][j] + 2.f * C[i1][0][j] + C[i2][0][j];
      float gz = A[i2][0][j] - A[i0][0][j];
      const float pm = sqrtf(fmaf(gx, gx, fmaf(gy, gy, fmaf(gz, gz, EPS))));
      gx = B[i0][1][j] + 2.f * B[i1][1][j] + B[i2][1][j];
      gy = C[i0][1][j] + 2.f * C[i1][1][j] + C[i2][1][j];
      gz = A[i2][1][j] - A[i0][1][j];
      const float tm = sqrtf(fmaf(gx, gx, fmaf(gy, gy, fmaf(gz, gz, EPS))));
      acc += fabsf(pm - tm);
    }
    __syncthreads();
  }

  // ---- reduction: wave shfl -> LDS -> one atomic per block ----
  float sred = acc;
#pragma unroll
  for (int off = 32; off > 0; off >>= 1) sred += __shfl_down(sred, off, 64);
  __shared__ float wsum[THREADS / 64];
  const int lane = tid & 63;
  const int wid = tid >> 6;
  if (lane == 0) wsum[wid] = sred;
  __syncthreads();
  if (tid == 0) {
    float t = 0.f;
#pragma unroll
    for (int i = 0; i < THREADS / 64; ++i) t += wsum[i];
    atomicAdd(out, t * (1.0f / (float)((size_t)Bd * Dd * Hd * Wd)));
  }
}

extern "C" void kernel_launch(void* const* d_in, const int* in_sizes, int n_in,
                              void* d_out, int out_size, void* d_ws, size_t ws_size,
                              hipStream_t stream) {
  const float* pred = (const float*)d_in[0];
  const float* targ = (const float*)d_in[1];
  float* out = (float*)d_out;
  (void)in_sizes; (void)n_in; (void)out_size; (void)d_ws; (void)ws_size;

  hipMemsetAsync(out, 0, sizeof(float), stream);
  dim3 grid(HGROUPS, NCHUNK, Bd);
  sobel_loss_kernel<<<grid, THREADS, 0, stream>>>(pred, targ, out);
}